// Round 18
// baseline (362.167 us; speedup 1.0000x reference)
//
#include <hip/hip_runtime.h>
#include <cstdint>
#include <cstddef>

typedef unsigned short u16;
typedef unsigned int u32;
typedef short bf16x8 __attribute__((ext_vector_type(8)));
typedef float f32x4 __attribute__((ext_vector_type(4)));

__device__ __forceinline__ float bf2f(u16 u){
  union { u32 i; float f; } c; c.i = ((u32)u) << 16; return c.f;
}
__device__ __forceinline__ u16 f2bf(float f){
  union { float f; u32 i; } c; c.f = f;
  u32 r = c.i + 0x7FFFu + ((c.i >> 16) & 1u);
  return (u16)(r >> 16);
}
__device__ __forceinline__ void gload_lds16(const void* g, void* l){
  __builtin_amdgcn_global_load_lds(
      (const __attribute__((address_space(1))) u32*)g,
      (__attribute__((address_space(3))) u32*)l, 16, 0, 0);
}

// ------- fused f32->bf16 conversion (11 segments) + bias concat, 1 launch --
struct ConvArgs {
  const float* src[11];
  u16* dst[11];
  u32 base[12];
  const float* b0; const float* b1; const float* b2;
  float* fbias;
};
__global__ __launch_bounds__(256)
void f32_to_bf16_multi(ConvArgs a){
  if (blockIdx.x == gridDim.x - 1){
    for (int i = threadIdx.x; i < 896; i += 256){
      float v;
      if (i < 128) v = a.b0[i];
      else if (i < 384) v = a.b1[i - 128];
      else v = a.b2[i - 384];
      a.fbias[i] = v;
    }
    return;
  }
  u32 i = blockIdx.x * 256 + threadIdx.x;
  if (i >= a.base[11]) return;
  int j = 0;
  #pragma unroll
  for (int k = 1; k < 11; ++k) j += (i >= a.base[k]);
  u32 li = i - a.base[j];
  const float4* s = (const float4*)a.src[j] + (size_t)li * 2;
  float4 va = s[0], vb = s[1];
  u16 o[8] = {f2bf(va.x),f2bf(va.y),f2bf(va.z),f2bf(va.w),
              f2bf(vb.x),f2bf(vb.y),f2bf(vb.z),f2bf(vb.w)};
  *(uint4*)(a.dst[j] + (size_t)li * 8) = *(const uint4*)o;
}

// ============ epilogue helper (EPI 0/1/2 only) ============
template<int EPI>
__device__ __forceinline__ void gemm_epilogue(
    f32x4 acc[4][4], const float* bias, void* Cv, int N, int ldc,
    const u16* I, const float* sw, int m0, int n0, int wr, int wc, int lane)
{
  float w0 = 0.f;
  if (EPI == 2){
    float s0 = sw[0], s1 = sw[1], s2 = sw[2];
    float mx = fmaxf(s0, fmaxf(s1, s2));
    float e0 = __expf(s0-mx), e1 = __expf(s1-mx), e2 = __expf(s2-mx);
    w0 = e0 / (e0 + e1 + e2);
  }
  u16*   C16 = (u16*)Cv;
  float* C32 = (float*)Cv;
  #pragma unroll
  for (int c=0;c<4;++c){
    int col = n0 + wc*64 + c*16 + (lane&15);
    float bv = bias[col];
    #pragma unroll
    for (int r=0;r<4;++r){
      int rbase = m0 + wr*64 + r*16 + (lane>>4)*4;
      #pragma unroll
      for (int e=0;e<4;++e){
        int row = rbase + e;
        float v = acc[r][c][e] + bv;
        if (EPI == 1) v = v / (1.f + __expf(-v));
        if (EPI == 2){
          v = bf2f(I[(size_t)row*ldc + col]) + w0 * v;
          C32[(size_t)row*ldc + col] = v;
        } else {
          C16[(size_t)row*ldc + col] = f2bf(v);
        }
      }
    }
  }
}

// ---------------- legacy 128x128 GEMM body (kept for small W2 GEMMs) -------
template<int EPI>
__device__ __forceinline__ void gemm_body(
    const u16* __restrict__ A, const u16* __restrict__ W,
    const float* __restrict__ bias, void* __restrict__ Cv,
    int N, int K, int lda, int ldc,
    const u16* __restrict__ I, const float* __restrict__ sw,
    int bx, int by)
{
  __shared__ __align__(16) u16 As[128*64];
  __shared__ __align__(16) u16 Bs[128*64];
  const int tid  = threadIdx.x;
  const int lane = tid & 63;
  const int wave = tid >> 6;
  const int wr = wave >> 1, wc = wave & 1;
  const int m0 = by * 128, n0 = bx * 128;

  f32x4 acc[4][4];
  #pragma unroll
  for (int r=0;r<4;++r)
    #pragma unroll
    for (int c=0;c<4;++c)
      #pragma unroll
      for (int e=0;e<4;++e) acc[r][c][e] = 0.f;

  int srow[4], soff[4];
  #pragma unroll
  for (int j=0;j<4;++j){
    int rr = (wave*4 + j)*8 + (lane>>3);
    srow[j] = rr;
    soff[j] = ((lane & 7) ^ (rr & 7)) * 8;
  }

  for (int k0 = 0; k0 < K; k0 += 64){
    #pragma unroll
    for (int j=0;j<4;++j){
      gload_lds16(A + (size_t)(m0 + srow[j])*lda + k0 + soff[j], As + (wave*4+j)*512);
      gload_lds16(W + (size_t)(n0 + srow[j])*K   + k0 + soff[j], Bs + (wave*4+j)*512);
    }
    __syncthreads();
    #pragma unroll
    for (int ks=0; ks<2; ++ks){
      bf16x8 af[4], bfr[4];
      #pragma unroll
      for (int r=0;r<4;++r){
        int row = wr*64 + r*16 + (lane&15);
        int cs  = (ks*4 + (lane>>4)) ^ (row & 7);
        af[r] = *(const bf16x8*)(As + row*64 + cs*8);
      }
      #pragma unroll
      for (int c=0;c<4;++c){
        int row = wc*64 + c*16 + (lane&15);
        int cs  = (ks*4 + (lane>>4)) ^ (row & 7);
        bfr[c] = *(const bf16x8*)(Bs + row*64 + cs*8);
      }
      #pragma unroll
      for (int r=0;r<4;++r)
        #pragma unroll
        for (int c=0;c<4;++c)
          acc[r][c] = __builtin_amdgcn_mfma_f32_16x16x32_bf16(af[r], bfr[c], acc[r][c], 0,0,0);
    }
    __syncthreads();
  }
  gemm_epilogue<EPI>(acc, bias, Cv, N, ldc, I, sw, m0, n0, wr, wc, lane);
}

// grouped expert-W2: mol(64 blk) | path(128 blk) | cell(256 blk), one launch
__global__ __launch_bounds__(256, 4)
void gemm_w2group(const u16* __restrict__ S1, u16* __restrict__ S2,
                  const u16* __restrict__ w0, const u16* __restrict__ w1,
                  const u16* __restrict__ w2, const float* __restrict__ b0,
                  const float* __restrict__ b1, const float* __restrict__ b2)
{
  int bx = blockIdx.x;
  if (bx < 64){
    gemm_body<0>(S1, w0, b0, S2, 128, 128, 896, 896, nullptr, nullptr, 0, bx);
  } else if (bx < 192){
    int l = bx - 64;
    gemm_body<0>(S1+128, w1, b1, S2+128, 256, 256, 896, 896, nullptr, nullptr, l>>6, l&63);
  } else {
    int l = bx - 192;
    gemm_body<0>(S1+384, w2, b2, S2+384, 512, 512, 896, 896, nullptr, nullptr, l>>6, l&63);
  }
}

// ======== deep-pipelined 256x128 GEMM (triple-buffer, counted vmcnt) =======
template<int EPI>
__device__ __forceinline__ void gemm_body2(
    u16* __restrict__ S,
    const u16* __restrict__ A, const u16* __restrict__ W,
    const float* __restrict__ bias, void* __restrict__ Cv,
    int N, int K, int lda, int ldc,
    const u16* __restrict__ I, const float* __restrict__ sw,
    int bx, int by)
{
  const int tid = threadIdx.x, lane = tid & 63, wave = tid >> 6;
  const int wr = wave >> 1, wc = wave & 1;     // wr 0..3, wc 0..1
  const int m0 = by * 256, n0 = bx * 128;

  f32x4 acc[4][4];
  #pragma unroll
  for (int r=0;r<4;++r)
    #pragma unroll
    for (int c=0;c<4;++c)
      #pragma unroll
      for (int e=0;e<4;++e) acc[r][c][e] = 0.f;

  const u16* src[6]; int dst6[6];
  #pragma unroll
  for (int i=0;i<6;++i){
    int c = i*512 + tid;
    int row = c >> 3, slot = c & 7;
    int soff = (slot ^ (row & 7)) * 8;
    src[i] = (row < 256) ? A + (size_t)(m0 + row)*lda + soff
                         : W + (size_t)(n0 + row - 256)*K + soff;
    dst6[i] = c * 8;
  }
  const int nt = K >> 6;
  auto stage = [&](int buf, int kt){
    u16* base = S + buf*24576;
    #pragma unroll
    for (int i=0;i<6;++i) gload_lds16(src[i] + kt*64, base + dst6[i]);
  };

  stage(0, 0);
  stage(1, 1);
  asm volatile("s_waitcnt vmcnt(6)" ::: "memory");
  __builtin_amdgcn_s_barrier();
  __builtin_amdgcn_sched_barrier(0);

  int cur = 0;
  for (int t = 0; t < nt; ++t){
    int nxt = (t + 2 < nt) ? t + 2 : nt - 1;
    int sb = cur + 2; if (sb >= 3) sb -= 3;
    stage(sb, nxt);

    const u16* As = S + cur*24576;
    const u16* Bs = As + 16384;
    __builtin_amdgcn_s_setprio(1);
    #pragma unroll
    for (int ks=0; ks<2; ++ks){
      bf16x8 af[4], bfr[4];
      #pragma unroll
      for (int r=0;r<4;++r){
        int row = wr*64 + r*16 + (lane&15);
        int cs  = (ks*4 + (lane>>4)) ^ (row & 7);
        af[r] = *(const bf16x8*)(As + row*64 + cs*8);
      }
      #pragma unroll
      for (int c=0;c<4;++c){
        int row = wc*64 + c*16 + (lane&15);
        int cs  = (ks*4 + (lane>>4)) ^ (row & 7);
        bfr[c] = *(const bf16x8*)(Bs + row*64 + cs*8);
      }
      #pragma unroll
      for (int r=0;r<4;++r)
        #pragma unroll
        for (int c=0;c<4;++c)
          acc[r][c] = __builtin_amdgcn_mfma_f32_16x16x32_bf16(af[r], bfr[c], acc[r][c], 0,0,0);
    }
    __builtin_amdgcn_s_setprio(0);
    asm volatile("s_waitcnt vmcnt(6)" ::: "memory");
    __builtin_amdgcn_sched_barrier(0);
    __builtin_amdgcn_s_barrier();
    __builtin_amdgcn_sched_barrier(0);
    cur += 1; if (cur >= 3) cur -= 3;
  }

  if (EPI == 3){
    u16* wt = S + wave*4096;
    #pragma unroll
    for (int c=0;c<4;++c){
      int pos = c*16 + (lane&15);
      int p2 = pos & 31, hp = pos >> 5;
      int kap = hp*32 + (p2 < 16 ? 2*p2 : 2*(p2-16)+1);   // inverse-pi
      #pragma unroll
      for (int r=0;r<4;++r){
        #pragma unroll
        for (int e=0;e<4;++e){
          int dl = r*16 + (lane>>4)*4 + e;
          float v = acc[r][c][e] + bias[m0 + wr*64 + dl];
          wt[dl*64 + ((((kap>>3) ^ dl) & 7)<<3) + (kap&7)] = f2bf(v);
        }
      }
    }
    int colbase = n0 + wc*64;
    u16* vt_out = (u16*)Cv;
    size_t vbase = (size_t)(colbase >> 11) * 2097152
                 + (size_t)((colbase & 2047) >> 6) * 64;
    #pragma unroll
    for (int i=0;i<8;++i){
      int idx = i*64 + lane;
      int dl = idx >> 3, kc = idx & 7;
      u16 tmp[8];
      #pragma unroll
      for (int j=0;j<8;++j) tmp[j] = wt[dl*64 + (((kc ^ dl) & 7)<<3) + j];
      *(uint4*)(vt_out + vbase + (size_t)(m0 + wr*64 + dl)*2048 + kc*8)
          = *(const uint4*)tmp;
    }
    return;
  }
  gemm_epilogue<EPI>(acc, bias, Cv, N, ldc, I, sw, m0, n0, wr, wc, lane);
}

template<int EPI>
__global__ __launch_bounds__(512, 1)
void gemm_bt2(const u16* __restrict__ A, const u16* __restrict__ W,
              const float* __restrict__ bias, void* __restrict__ Cv,
              int N, int K, int lda, int ldc,
              const u16* __restrict__ I, const float* __restrict__ sw)
{
  __shared__ __align__(16) u16 S[3*24576];
  gemm_body2<EPI>(S, A, W, bias, Cv, N, K, lda, ldc, I, sw, blockIdx.x, blockIdx.y);
}

// grouped qkv (Q|K, N=2048, 512 blk) + V^T (256 blk), deep-pipelined.
__global__ __launch_bounds__(512, 1)
void gemm_qkv_vt2(const u16* __restrict__ integ, const u16* __restrict__ Wqkv,
                  const float* __restrict__ bqkv, u16* __restrict__ qkv,
                  u16* __restrict__ vt)
{
  __shared__ __align__(16) u16 S[3*24576];
  int bx = blockIdx.x;
  if (bx < 512){
    gemm_body2<0>(S, integ, Wqkv, bqkv, qkv, 2048, 1024, 1024, 3072,
                  nullptr, nullptr, bx & 15, bx >> 4);
  } else {
    int l = bx - 512;
    gemm_body2<3>(S, Wqkv + (size_t)2048*1024, integ, bqkv + 2048, vt, 8192, 1024,
                  1024, 2048, nullptr, nullptr, l & 63, l >> 6);
  }
}

// ---------------- LayerNorm bodies ----------------
template<int D>
__device__ __forceinline__ void ln_body_masked(
    u16* __restrict__ H, int ldh, const float* __restrict__ g,
    const float* __restrict__ beta, const int* __restrict__ st,
    int eid, float* __restrict__ outp)
{
  const int tid = threadIdx.x, lane = tid & 63, wave = tid >> 6;
  const int token = blockIdx.x * 4 + wave;
  constexpr int VPT = D / 64;
  float v[VPT];
  u16* row = H + (size_t)token * ldh + lane * VPT;
  #pragma unroll
  for (int i=0;i<VPT/2;++i){
    u32 u = ((const u32*)row)[i];
    v[2*i]   = bf2f((u16)(u & 0xFFFFu));
    v[2*i+1] = bf2f((u16)(u >> 16));
  }
  float s = 0.f;
  #pragma unroll
  for (int i=0;i<VPT;++i) s += v[i];
  #pragma unroll
  for (int off=1; off<64; off<<=1) s += __shfl_xor(s, off);
  float mu = s * (1.f / D);
  float q = 0.f;
  #pragma unroll
  for (int i=0;i<VPT;++i){ float d = v[i] - mu; q += d * d; }
  #pragma unroll
  for (int off=1; off<64; off<<=1) q += __shfl_xor(q, off);
  float rs = rsqrtf(q * (1.f / D) + 1e-5f);
  float msk = (st[token] == eid) ? 1.f : 0.f;
  #pragma unroll
  for (int i=0;i<VPT;++i){
    float gg = g[lane*VPT + i];
    float bb = beta[lane*VPT + i];
    float val = (gg * (v[i] - mu) * rs + bb) * msk;
    outp[(size_t)token * D + lane * VPT + i] = val;
    row[i] = f2bf(val);
  }
}

__global__ __launch_bounds__(256, 4)
void ln_expert(u16* __restrict__ S2,
               const float* __restrict__ g0, const float* __restrict__ be0,
               const float* __restrict__ g1, const float* __restrict__ be1,
               const float* __restrict__ g2, const float* __restrict__ be2,
               const int* __restrict__ st,
               float* __restrict__ o0, float* __restrict__ o1,
               float* __restrict__ o2)
{
  if (blockIdx.y == 0)      ln_body_masked<128>(S2,     896, g0, be0, st, 0, o0);
  else if (blockIdx.y == 1) ln_body_masked<256>(S2+128, 896, g1, be1, st, 1, o1);
  else                      ln_body_masked<512>(S2+384, 896, g2, be2, st, 2, o2);
}

__global__ __launch_bounds__(256, 4)
void ln_int(const u16* __restrict__ H, const float* __restrict__ g,
            const float* __restrict__ beta, u16* __restrict__ outp)
{
  const int tid = threadIdx.x, lane = tid & 63, wave = tid >> 6;
  const int token = blockIdx.x * 4 + wave;
  constexpr int D = 1024, VPT = 16;
  float v[VPT];
  const u16* row = H + (size_t)token * D + lane * VPT;
  #pragma unroll
  for (int i=0;i<VPT/2;++i){
    u32 u = ((const u32*)row)[i];
    v[2*i]   = bf2f((u16)(u & 0xFFFFu));
    v[2*i+1] = bf2f((u16)(u >> 16));
  }
  float s = 0.f;
  #pragma unroll
  for (int i=0;i<VPT;++i) s += v[i];
  #pragma unroll
  for (int off=1; off<64; off<<=1) s += __shfl_xor(s, off);
  float mu = s * (1.f / D);
  float q = 0.f;
  #pragma unroll
  for (int i=0;i<VPT;++i){ float d = v[i] - mu; q += d * d; }
  #pragma unroll
  for (int off=1; off<64; off<<=1) q += __shfl_xor(q, off);
  float rs = rsqrtf(q * (1.f / D) + 1e-5f);
  #pragma unroll
  for (int i=0;i<VPT;++i){
    float val = g[lane*VPT + i] * (v[i] - mu) * rs + beta[lane*VPT + i];
    outp[(size_t)token * D + lane * VPT + i] = f2bf(val);
  }
}

// ---------------- flash attention v11 (B=4,S=2048,H=8,Dh=128) --------------
// 8 waves / 512 threads per block: two q-tiles (128 q-rows) SHARE one Ks/Vs
// staging pass. Per-wave algebra identical to v10 (16 q-rows); staging work
// and K/V traffic per q-row halve. LDS 48KB -> 2 blocks/CU; grid 512 = one
// exact residency round. vmcnt counts re-derived for 2-load stages.
__global__ __launch_bounds__(512, 2)
void flash_attn(const u16* __restrict__ qkv, const u16* __restrict__ vt,
                u16* __restrict__ o)
{
  __shared__ __align__(16) u16 Ks[8192];    // [64 kv][128 d], chunk-XOR'd
  __shared__ __align__(16) u16 Vs[8192];    // [128 d][64 kappa], chunk-XOR'd
  __shared__ __align__(16) u16 Ps[8*1024];  // per-wave [16 q][64], chunk-XOR'd
  const int tid = threadIdx.x, lane = tid & 63, wave = tid >> 6;
  const int b = blockIdx.z, h = blockIdx.y, q0 = blockIdx.x * 128;
  const float cl2   = 0.12751791892f;
  const float DEFER = 90.50966799187809f;

  bf16x8 qreg[4];
  {
    const u16* qrow = qkv + (size_t)(b*2048 + q0 + wave*16 + (lane&15))*3072
                      + h*128 + (lane>>4)*8;
    #pragma unroll
    for (int kk=0;kk<4;++kk) qreg[kk] = *(const bf16x8*)(qrow + kk*32);
  }
  asm volatile("s_waitcnt vmcnt(0)" ::: "memory");

  // staging: 8 waves x 2 chunks x 64 lanes x 16B covers both 16KB tiles
  const u16* ksrc[2]; const u16* vsrc[2]; int cdst[2];
  #pragma unroll
  for (int i=0;i<2;++i){
    int cidx = (wave*2 + i)*64 + lane;
    int krow = cidx >> 4, kcs = cidx & 15;
    int kcsrc = (kcs & 8) | ((kcs & 7) ^ (krow & 7));
    ksrc[i] = qkv + (size_t)(b*2048 + krow)*3072 + h*128 + 1024 + kcsrc*8;
    int vd = cidx >> 3, vcs = cidx & 7;
    vsrc[i] = vt + ((size_t)(b*8 + h)*128 + vd)*2048 + (vcs ^ (vd & 7))*8;
    cdst[i] = cidx * 8;
  }

  int koff[16];
  #pragma unroll
  for (int kk=0;kk<4;++kk)
    #pragma unroll
    for (int cb=0;cb<4;++cb){
      int row  = (lane&15) + 16*cb;
      int c    = kk*4 + (lane>>4);
      int slot = (c & 8) | ((c & 7) ^ (row & 7));
      koff[kk*4+cb] = (row*128 + slot*8) * 2;
    }
  int voff[16];
  #pragma unroll
  for (int kk=0;kk<2;++kk)
    #pragma unroll
    for (int f=0;f<8;++f){
      int d = f*16 + (lane&15);
      int c = kk*4 + (lane>>4);
      voff[kk*8+f] = (d*64 + (c ^ (d & 7))*8) * 2;
    }
  int pwoff[8];
  #pragma unroll
  for (int e=0;e<4;++e){
    int prow = (lane>>4)*4 + e;
    int j01 = lane & 15;
    int j23 = 16 + (lane & 15);
    pwoff[e*2]   = (prow*32 + (((((j01>>2) ^ (prow&7)) & 7)<<2) | (j01&3))) * 4;
    pwoff[e*2+1] = (prow*32 + (((((j23>>2) ^ (prow&7)) & 7)<<2) | (j23&3))) * 4;
  }
  int proff[2];
  #pragma unroll
  for (int kk=0;kk<2;++kk){
    int prow = lane & 15;
    int pc   = kk*4 + (lane>>4);
    proff[kk] = (prow*64 + ((pc ^ (prow & 7)) & 7)*8) * 2;
  }

  auto stageK = [&](){
    #pragma unroll
    for (int i=0;i<2;++i){ gload_lds16(ksrc[i], Ks + cdst[i]); ksrc[i] += 196608; }
  };
  auto stageV = [&](){
    #pragma unroll
    for (int i=0;i<2;++i){ gload_lds16(vsrc[i], Vs + cdst[i]); vsrc[i] += 64; }
  };

  f32x4 oacc[8];
  #pragma unroll
  for (int f=0;f<8;++f)
    #pragma unroll
    for (int e=0;e<4;++e) oacc[f][e] = 0.f;
  float m_run[4] = {-3e38f,-3e38f,-3e38f,-3e38f};
  float l_run[4] = {0.f,0.f,0.f,0.f};
  const char* KsB = (const char*)Ks;
  const char* VsB = (const char*)Vs;
  char* PsWB = (char*)(Ps + wave*1024);

  // prologue: K[0](2) + V[0](2) in flight; wait K[0] (2 newest = V[0] out)
  stageK();
  stageV();
  asm volatile("s_waitcnt vmcnt(2)" ::: "memory");
  __builtin_amdgcn_s_barrier();
  __builtin_amdgcn_sched_barrier(0);

  for (int kt=0; kt<32; ++kt){
    f32x4 s[4];
    #pragma unroll
    for (int cb=0;cb<4;++cb)
      #pragma unroll
      for (int e=0;e<4;++e) s[cb][e] = 0.f;
    __builtin_amdgcn_s_setprio(1);
    #pragma unroll
    for (int kk=0;kk<4;++kk){
      #pragma unroll
      for (int cb=0;cb<4;++cb){
        bf16x8 bk = *(const bf16x8*)(KsB + koff[kk*4+cb]);
        s[cb] = __builtin_amdgcn_mfma_f32_16x16x32_bf16(qreg[kk], bk, s[cb], 0,0,0);
      }
    }
    __builtin_amdgcn_s_setprio(0);
    asm volatile("s_waitcnt lgkmcnt(0)" ::: "memory");
    __builtin_amdgcn_sched_barrier(0);
    __builtin_amdgcn_s_barrier();
    __builtin_amdgcn_sched_barrier(0);
    stageK();                               // K[kt+1] lands under softmax+PV

    #pragma unroll
    for (int e=0;e<4;++e){
      float t0 = s[0][e], t1 = s[1][e], t2 = s[2][e], t3 = s[3][e];
      float lmx = fmaxf(fmaxf(t0,t1), fmaxf(t2,t3));
      if (__any(lmx > m_run[e] + DEFER)){
        float mx = lmx;
        #pragma unroll
        for (int off=1; off<16; off<<=1) mx = fmaxf(mx, __shfl_xor(mx, off));
        float mnew = fmaxf(m_run[e], mx);
        float a = exp2f((m_run[e] - mnew) * cl2);
        m_run[e] = mnew;
        l_run[e] *= a;
        #pragma unroll
        for (int f=0;f<8;++f) oacc[f][e] *= a;
      }
      float ms = m_run[e];
      float p0 = exp2f((t0 - ms)*cl2), p1 = exp2f((t1 - ms)*cl2);
      float p2 = exp2f((t2 - ms)*cl2), p3 = exp2f((t3 - ms)*cl2);
      l_run[e] += (p0 + p1) + (p2 + p3);
      u32 c01, c23;
      asm("v_cvt_pk_bf16_f32 %0, %1, %2" : "=v"(c01) : "v"(p0), "v"(p1));
      asm("v_cvt_pk_bf16_f32 %0, %1, %2" : "=v"(c23) : "v"(p2), "v"(p3));
      *(u32*)(PsWB + pwoff[e*2])   = c01;
      *(u32*)(PsWB + pwoff[e*2+1]) = c23;
    }

    // V[kt] ready: outstanding = V[kt](2, oldest) + K[kt+1](2, newest)
    asm volatile("s_waitcnt vmcnt(2)" ::: "memory");
    __builtin_amdgcn_sched_barrier(0);
    __builtin_amdgcn_s_barrier();
    __builtin_amdgcn_sched_barrier(0);

    __builtin_amdgcn_s_setprio(1);
    #pragma unroll
    for (int kk=0;kk<2;++kk){
      bf16x8 pa = *(const bf16x8*)(PsWB + proff[kk]);
      #pragma unroll
      for (int f=0;f<8;++f){
        bf16x8 vb = *(const bf16x8*)(VsB + voff[kk*8+f]);
        oacc[f] = __builtin_amdgcn_mfma_f32_16x16x32_bf16(pa, vb, oacc[f], 0,0,0);
      }
    }
    __builtin_amdgcn_s_setprio(0);
    asm volatile("s_waitcnt lgkmcnt(0) vmcnt(0)" ::: "memory");
    __builtin_amdgcn_sched_barrier(0);
    __builtin_amdgcn_s_barrier();
    __builtin_amdgcn_sched_barrier(0);
    if (kt + 1 < 32) stageV();              // V[kt+1] lands under next QK
  }

  #pragma unroll
  for (int e=0;e<4;++e){
    float l = l_run[e];
    #pragma unroll
    for (int off=1; off<16; off<<=1) l += __shfl_xor(l, off);
    l_run[e] = 1.f / l;
  }
  #pragma unroll
  for (int f=0;f<8;++f)
    #pragma unroll
    for (int e=0;e<4;++e){
      int row = q0 + wave*16 + (lane>>4)*4 + e;
      int col = h*128 + f*16 + (lane&15);
      o[(size_t)(b*2048 + row)*1024 + col] = f2bf(oacc[f][e] * l_run[e]);
    }
}

// ---------------- launch ----------------
extern "C" void kernel_launch(void* const* d_in, const int* in_sizes, int n_in,
                              void* d_out, int out_size, void* d_ws, size_t ws_size,
                              hipStream_t stream)
{
  const float* x         = (const float*)d_in[0];
  const int*   stypes    = (const int*)d_in[1];
  const float* mol_W1    = (const float*)d_in[2];
  const float* mol_b1    = (const float*)d_in[3];
  const float* mol_W2    = (const float*)d_in[4];
  const float* mol_b2    = (const float*)d_in[5];
  const float* mol_g     = (const float*)d_in[6];
  const float* mol_beta  = (const float*)d_in[7];
  const float* path_W1   = (const float*)d_in[8];
  const float* path_b1   = (const float*)d_in[9];
  const float* path_W2   = (const float*)d_in[10];
  const float* path_b2   = (const float*)d_in[11];
  const float* path_g    = (const float*)d_in[12];
  const float* path_beta = (const float*)d_in[13];
  const float* cell_W1   = (const float*)d_in[14];
  const float* cell_b1   = (const float*)d_in[15];
  const float* cell_W2   = (const float*)d_in[16];
  const float* cell_b2   = (const float*)d_in[17];
  const float* cell_g    = (const float*)d_in[18];
  const float* cell_beta = (const float*)d_in[19];
  const float* int_W1    = (const float*)d_in[20];
  const float* int_b1    = (const float*)d_in[21];
  const float* int_W2    = (const float*)d_in[22];
  const float* int_b2    = (const float*)d_in[23];
  const float* int_g     = (const float*)d_in[24];
  const float* int_beta  = (const float*)d_in[25];
  const float* attn_Wqkv = (const float*)d_in[26];
  const float* attn_bqkv = (const float*)d_in[27];
  const float* attn_Wo   = (const float*)d_in[28];
  const float* attn_bo   = (const float*)d_in[29];
  const float* scale_w   = (const float*)d_in[30];

  float* out_final = (float*)d_out;           // [8192,1024] f32
  float* out_mol   = out_final + 8388608;     // [8192,128]  f32
  float* out_path  = out_mol   + 1048576;     // [8192,256]  f32
  float* out_cell  = out_path  + 2097152;     // [8192,512]  f32

  u16* ws    = (u16*)d_ws;
  u16* qkv   = ws;                  // 8192*3072 (early: xb; V third unused)
  u16* integ = qkv   + 25165824;    // 8192*1024
  u16* S1    = integ + 8388608;     // 8192*1024 scratch
  u16* S2    = S1    + 8388608;     // 8192*1024 scratch (cat / later vt)
  u16* wb    = S2    + 8388608;     // bf16 weights
  u16* xb    = qkv;                 // [8192,1024] bf16 (dead before qkv GEMM)

  u16* w1f    = wb;                  // fused expert W1 [896][1024]
  u16* molW2b = w1f    + 917504;
  u16* pathW2b= molW2b + 16384;
  u16* cellW2b= pathW2b+ 65536;
  u16* intW1b = cellW2b+ 262144;
  u16* intW2b = intW1b + 917504;
  u16* qkvWb  = intW2b + 1048576;
  u16* woWb   = qkvWb  + 3145728;
  float* fbias= (float*)(woWb + 1048576);  // 896 f32

  dim3 blk(256);
  dim3 blk2(512);

  ConvArgs ca;
  const float* srcs[11] = {x, mol_W1, path_W1, cell_W1, mol_W2, path_W2,
                           cell_W2, int_W1, int_W2, attn_Wqkv, attn_Wo};
  u16* dsts[11] = {xb, w1f, w1f + 131072, w1f + 393216, molW2b, pathW2b,
                   cellW2b, intW1b, intW2b, qkvWb, woWb};
  u32 n8s[11] = {1048576, 16384, 32768, 65536, 2048, 8192,
                 32768, 114688, 131072, 393216, 131072};
  u32 acc8 = 0;
  for (int i=0;i<11;++i){ ca.src[i]=srcs[i]; ca.dst[i]=dsts[i]; ca.base[i]=acc8; acc8+=n8s[i]; }
  ca.base[11] = acc8;
  ca.b0 = mol_b1; ca.b1 = path_b1; ca.b2 = cell_b1; ca.fbias = fbias;
  f32_to_bf16_multi<<<(acc8 + 255)/256 + 1, blk, 0, stream>>>(ca);

  // fused expert W1: silu(x @ W1f^T + b1f) -> S1 [8192,896]   (256x128 tiles)
  gemm_bt2<1><<<dim3(7,32), blk2, 0, stream>>>(xb, w1f, fbias, S1, 896, 1024, 1024, 896, nullptr, nullptr);
  // grouped expert W2 -> S2 [8192,896]  (legacy 128x128)
  gemm_w2group<<<448, blk, 0, stream>>>(S1, S2, molW2b, pathW2b, cellW2b,
                                        mol_b2, path_b2, cell_b2);
  // grouped expert LNs
  ln_expert<<<dim3(2048,3), blk, 0, stream>>>(S2, mol_g, mol_beta, path_g,
                                              path_beta, cell_g, cell_beta,
                                              stypes, out_mol, out_path, out_cell);

  // integration (256x128 tiles)
  gemm_bt2<1><<<dim3(8,32), blk2, 0, stream>>>(S2, intW1b, int_b1, S1, 1024, 896,  896,  1024, nullptr, nullptr);
  gemm_bt2<0><<<dim3(8,32), blk2, 0, stream>>>(S1, intW2b, int_b2, S2, 1024, 1024, 1024, 1024, nullptr, nullptr);
  ln_int<<<2048, blk, 0, stream>>>(S2, int_g, int_beta, integ);

  // attention: grouped Q|K (512 blk) + V^T (256 blk, coalesced epilogue)
  gemm_qkv_vt2<<<768, blk2, 0, stream>>>(integ, qkvWb, attn_bqkv, qkv, S2);
  flash_attn<<<dim3(16,8,4), blk2, 0, stream>>>(qkv, S2, S1);

  // final = integ + w0*(o @ Wo^T + bo), f32 out (256x128 tiles)
  gemm_bt2<2><<<dim3(8,32), blk2, 0, stream>>>(S1, woWb, attn_bo, out_final, 1024, 1024, 1024, 1024, integ, scale_w);
}

// Round 19
// 321.820 us; speedup vs baseline: 1.1254x; 1.1254x over previous
//
#include <hip/hip_runtime.h>
#include <cstdint>
#include <cstddef>

typedef unsigned short u16;
typedef unsigned int u32;
typedef short bf16x8 __attribute__((ext_vector_type(8)));
typedef float f32x4 __attribute__((ext_vector_type(4)));

__device__ __forceinline__ float bf2f(u16 u){
  union { u32 i; float f; } c; c.i = ((u32)u) << 16; return c.f;
}
__device__ __forceinline__ u16 f2bf(float f){
  union { float f; u32 i; } c; c.f = f;
  u32 r = c.i + 0x7FFFu + ((c.i >> 16) & 1u);
  return (u16)(r >> 16);
}
__device__ __forceinline__ void gload_lds16(const void* g, void* l){
  __builtin_amdgcn_global_load_lds(
      (const __attribute__((address_space(1))) u32*)g,
      (__attribute__((address_space(3))) u32*)l, 16, 0, 0);
}

// ------- fused f32->bf16 conversion (11 segments) + bias concat, 1 launch --
struct ConvArgs {
  const float* src[11];
  u16* dst[11];
  u32 base[12];
  const float* b0; const float* b1; const float* b2;
  float* fbias;
};
__global__ __launch_bounds__(256)
void f32_to_bf16_multi(ConvArgs a){
  if (blockIdx.x == gridDim.x - 1){
    for (int i = threadIdx.x; i < 896; i += 256){
      float v;
      if (i < 128) v = a.b0[i];
      else if (i < 384) v = a.b1[i - 128];
      else v = a.b2[i - 384];
      a.fbias[i] = v;
    }
    return;
  }
  u32 i = blockIdx.x * 256 + threadIdx.x;
  if (i >= a.base[11]) return;
  int j = 0;
  #pragma unroll
  for (int k = 1; k < 11; ++k) j += (i >= a.base[k]);
  u32 li = i - a.base[j];
  const float4* s = (const float4*)a.src[j] + (size_t)li * 2;
  float4 va = s[0], vb = s[1];
  u16 o[8] = {f2bf(va.x),f2bf(va.y),f2bf(va.z),f2bf(va.w),
              f2bf(vb.x),f2bf(vb.y),f2bf(vb.z),f2bf(vb.w)};
  *(uint4*)(a.dst[j] + (size_t)li * 8) = *(const uint4*)o;
}

// ============ epilogue helper (EPI 0/1/2 only) ============
template<int EPI>
__device__ __forceinline__ void gemm_epilogue(
    f32x4 acc[4][4], const float* bias, void* Cv, int N, int ldc,
    const u16* I, const float* sw, int m0, int n0, int wr, int wc, int lane)
{
  float w0 = 0.f;
  if (EPI == 2){
    float s0 = sw[0], s1 = sw[1], s2 = sw[2];
    float mx = fmaxf(s0, fmaxf(s1, s2));
    float e0 = __expf(s0-mx), e1 = __expf(s1-mx), e2 = __expf(s2-mx);
    w0 = e0 / (e0 + e1 + e2);
  }
  u16*   C16 = (u16*)Cv;
  float* C32 = (float*)Cv;
  #pragma unroll
  for (int c=0;c<4;++c){
    int col = n0 + wc*64 + c*16 + (lane&15);
    float bv = bias[col];
    #pragma unroll
    for (int r=0;r<4;++r){
      int rbase = m0 + wr*64 + r*16 + (lane>>4)*4;
      #pragma unroll
      for (int e=0;e<4;++e){
        int row = rbase + e;
        float v = acc[r][c][e] + bv;
        if (EPI == 1) v = v / (1.f + __expf(-v));
        if (EPI == 2){
          v = bf2f(I[(size_t)row*ldc + col]) + w0 * v;
          C32[(size_t)row*ldc + col] = v;
        } else {
          C16[(size_t)row*ldc + col] = f2bf(v);
        }
      }
    }
  }
}

// ---------------- legacy 128x128 GEMM body (kept for small W2 GEMMs) -------
template<int EPI>
__device__ __forceinline__ void gemm_body(
    const u16* __restrict__ A, const u16* __restrict__ W,
    const float* __restrict__ bias, void* __restrict__ Cv,
    int N, int K, int lda, int ldc,
    const u16* __restrict__ I, const float* __restrict__ sw,
    int bx, int by)
{
  __shared__ __align__(16) u16 As[128*64];
  __shared__ __align__(16) u16 Bs[128*64];
  const int tid  = threadIdx.x;
  const int lane = tid & 63;
  const int wave = tid >> 6;
  const int wr = wave >> 1, wc = wave & 1;
  const int m0 = by * 128, n0 = bx * 128;

  f32x4 acc[4][4];
  #pragma unroll
  for (int r=0;r<4;++r)
    #pragma unroll
    for (int c=0;c<4;++c)
      #pragma unroll
      for (int e=0;e<4;++e) acc[r][c][e] = 0.f;

  int srow[4], soff[4];
  #pragma unroll
  for (int j=0;j<4;++j){
    int rr = (wave*4 + j)*8 + (lane>>3);
    srow[j] = rr;
    soff[j] = ((lane & 7) ^ (rr & 7)) * 8;
  }

  for (int k0 = 0; k0 < K; k0 += 64){
    #pragma unroll
    for (int j=0;j<4;++j){
      gload_lds16(A + (size_t)(m0 + srow[j])*lda + k0 + soff[j], As + (wave*4+j)*512);
      gload_lds16(W + (size_t)(n0 + srow[j])*K   + k0 + soff[j], Bs + (wave*4+j)*512);
    }
    __syncthreads();
    #pragma unroll
    for (int ks=0; ks<2; ++ks){
      bf16x8 af[4], bfr[4];
      #pragma unroll
      for (int r=0;r<4;++r){
        int row = wr*64 + r*16 + (lane&15);
        int cs  = (ks*4 + (lane>>4)) ^ (row & 7);
        af[r] = *(const bf16x8*)(As + row*64 + cs*8);
      }
      #pragma unroll
      for (int c=0;c<4;++c){
        int row = wc*64 + c*16 + (lane&15);
        int cs  = (ks*4 + (lane>>4)) ^ (row & 7);
        bfr[c] = *(const bf16x8*)(Bs + row*64 + cs*8);
      }
      #pragma unroll
      for (int r=0;r<4;++r)
        #pragma unroll
        for (int c=0;c<4;++c)
          acc[r][c] = __builtin_amdgcn_mfma_f32_16x16x32_bf16(af[r], bfr[c], acc[r][c], 0,0,0);
    }
    __syncthreads();
  }
  gemm_epilogue<EPI>(acc, bias, Cv, N, ldc, I, sw, m0, n0, wr, wc, lane);
}

// grouped expert-W2: mol(64 blk) | path(128 blk) | cell(256 blk), one launch
__global__ __launch_bounds__(256, 4)
void gemm_w2group(const u16* __restrict__ S1, u16* __restrict__ S2,
                  const u16* __restrict__ w0, const u16* __restrict__ w1,
                  const u16* __restrict__ w2, const float* __restrict__ b0,
                  const float* __restrict__ b1, const float* __restrict__ b2)
{
  int bx = blockIdx.x;
  if (bx < 64){
    gemm_body<0>(S1, w0, b0, S2, 128, 128, 896, 896, nullptr, nullptr, 0, bx);
  } else if (bx < 192){
    int l = bx - 64;
    gemm_body<0>(S1+128, w1, b1, S2+128, 256, 256, 896, 896, nullptr, nullptr, l>>6, l&63);
  } else {
    int l = bx - 192;
    gemm_body<0>(S1+384, w2, b2, S2+384, 512, 512, 896, 896, nullptr, nullptr, l>>6, l&63);
  }
}

// ======== deep-pipelined 256x128 GEMM (triple-buffer, counted vmcnt) =======
template<int EPI>
__device__ __forceinline__ void gemm_body2(
    u16* __restrict__ S,
    const u16* __restrict__ A, const u16* __restrict__ W,
    const float* __restrict__ bias, void* __restrict__ Cv,
    int N, int K, int lda, int ldc,
    const u16* __restrict__ I, const float* __restrict__ sw,
    int bx, int by)
{
  const int tid = threadIdx.x, lane = tid & 63, wave = tid >> 6;
  const int wr = wave >> 1, wc = wave & 1;     // wr 0..3, wc 0..1
  const int m0 = by * 256, n0 = bx * 128;

  f32x4 acc[4][4];
  #pragma unroll
  for (int r=0;r<4;++r)
    #pragma unroll
    for (int c=0;c<4;++c)
      #pragma unroll
      for (int e=0;e<4;++e) acc[r][c][e] = 0.f;

  const u16* src[6]; int dst6[6];
  #pragma unroll
  for (int i=0;i<6;++i){
    int c = i*512 + tid;
    int row = c >> 3, slot = c & 7;
    int soff = (slot ^ (row & 7)) * 8;
    src[i] = (row < 256) ? A + (size_t)(m0 + row)*lda + soff
                         : W + (size_t)(n0 + row - 256)*K + soff;
    dst6[i] = c * 8;
  }
  const int nt = K >> 6;
  auto stage = [&](int buf, int kt){
    u16* base = S + buf*24576;
    #pragma unroll
    for (int i=0;i<6;++i) gload_lds16(src[i] + kt*64, base + dst6[i]);
  };

  stage(0, 0);
  stage(1, 1);
  asm volatile("s_waitcnt vmcnt(6)" ::: "memory");
  __builtin_amdgcn_s_barrier();
  __builtin_amdgcn_sched_barrier(0);

  int cur = 0;
  for (int t = 0; t < nt; ++t){
    int nxt = (t + 2 < nt) ? t + 2 : nt - 1;
    int sb = cur + 2; if (sb >= 3) sb -= 3;
    stage(sb, nxt);

    const u16* As = S + cur*24576;
    const u16* Bs = As + 16384;
    __builtin_amdgcn_s_setprio(1);
    #pragma unroll
    for (int ks=0; ks<2; ++ks){
      bf16x8 af[4], bfr[4];
      #pragma unroll
      for (int r=0;r<4;++r){
        int row = wr*64 + r*16 + (lane&15);
        int cs  = (ks*4 + (lane>>4)) ^ (row & 7);
        af[r] = *(const bf16x8*)(As + row*64 + cs*8);
      }
      #pragma unroll
      for (int c=0;c<4;++c){
        int row = wc*64 + c*16 + (lane&15);
        int cs  = (ks*4 + (lane>>4)) ^ (row & 7);
        bfr[c] = *(const bf16x8*)(Bs + row*64 + cs*8);
      }
      #pragma unroll
      for (int r=0;r<4;++r)
        #pragma unroll
        for (int c=0;c<4;++c)
          acc[r][c] = __builtin_amdgcn_mfma_f32_16x16x32_bf16(af[r], bfr[c], acc[r][c], 0,0,0);
    }
    __builtin_amdgcn_s_setprio(0);
    asm volatile("s_waitcnt vmcnt(6)" ::: "memory");
    __builtin_amdgcn_sched_barrier(0);
    __builtin_amdgcn_s_barrier();
    __builtin_amdgcn_sched_barrier(0);
    cur += 1; if (cur >= 3) cur -= 3;
  }

  if (EPI == 3){
    u16* wt = S + wave*4096;
    #pragma unroll
    for (int c=0;c<4;++c){
      int pos = c*16 + (lane&15);
      int p2 = pos & 31, hp = pos >> 5;
      int kap = hp*32 + (p2 < 16 ? 2*p2 : 2*(p2-16)+1);   // inverse-pi
      #pragma unroll
      for (int r=0;r<4;++r){
        #pragma unroll
        for (int e=0;e<4;++e){
          int dl = r*16 + (lane>>4)*4 + e;
          float v = acc[r][c][e] + bias[m0 + wr*64 + dl];
          wt[dl*64 + ((((kap>>3) ^ dl) & 7)<<3) + (kap&7)] = f2bf(v);
        }
      }
    }
    int colbase = n0 + wc*64;
    u16* vt_out = (u16*)Cv;
    size_t vbase = (size_t)(colbase >> 11) * 2097152
                 + (size_t)((colbase & 2047) >> 6) * 64;
    #pragma unroll
    for (int i=0;i<8;++i){
      int idx = i*64 + lane;
      int dl = idx >> 3, kc = idx & 7;
      u16 tmp[8];
      #pragma unroll
      for (int j=0;j<8;++j) tmp[j] = wt[dl*64 + (((kc ^ dl) & 7)<<3) + j];
      *(uint4*)(vt_out + vbase + (size_t)(m0 + wr*64 + dl)*2048 + kc*8)
          = *(const uint4*)tmp;
    }
    return;
  }
  gemm_epilogue<EPI>(acc, bias, Cv, N, ldc, I, sw, m0, n0, wr, wc, lane);
}

template<int EPI>
__global__ __launch_bounds__(512, 1)
void gemm_bt2(const u16* __restrict__ A, const u16* __restrict__ W,
              const float* __restrict__ bias, void* __restrict__ Cv,
              int N, int K, int lda, int ldc,
              const u16* __restrict__ I, const float* __restrict__ sw)
{
  __shared__ __align__(16) u16 S[3*24576];
  gemm_body2<EPI>(S, A, W, bias, Cv, N, K, lda, ldc, I, sw, blockIdx.x, blockIdx.y);
}

// grouped qkv (Q|K, N=2048, 512 blk) + V^T (256 blk), deep-pipelined.
__global__ __launch_bounds__(512, 1)
void gemm_qkv_vt2(const u16* __restrict__ integ, const u16* __restrict__ Wqkv,
                  const float* __restrict__ bqkv, u16* __restrict__ qkv,
                  u16* __restrict__ vt)
{
  __shared__ __align__(16) u16 S[3*24576];
  int bx = blockIdx.x;
  if (bx < 512){
    gemm_body2<0>(S, integ, Wqkv, bqkv, qkv, 2048, 1024, 1024, 3072,
                  nullptr, nullptr, bx & 15, bx >> 4);
  } else {
    int l = bx - 512;
    gemm_body2<3>(S, Wqkv + (size_t)2048*1024, integ, bqkv + 2048, vt, 8192, 1024,
                  1024, 2048, nullptr, nullptr, l & 63, l >> 6);
  }
}

// ---------------- LayerNorm bodies ----------------
template<int D>
__device__ __forceinline__ void ln_body_masked(
    u16* __restrict__ H, int ldh, const float* __restrict__ g,
    const float* __restrict__ beta, const int* __restrict__ st,
    int eid, float* __restrict__ outp)
{
  const int tid = threadIdx.x, lane = tid & 63, wave = tid >> 6;
  const int token = blockIdx.x * 4 + wave;
  constexpr int VPT = D / 64;
  float v[VPT];
  u16* row = H + (size_t)token * ldh + lane * VPT;
  #pragma unroll
  for (int i=0;i<VPT/2;++i){
    u32 u = ((const u32*)row)[i];
    v[2*i]   = bf2f((u16)(u & 0xFFFFu));
    v[2*i+1] = bf2f((u16)(u >> 16));
  }
  float s = 0.f;
  #pragma unroll
  for (int i=0;i<VPT;++i) s += v[i];
  #pragma unroll
  for (int off=1; off<64; off<<=1) s += __shfl_xor(s, off);
  float mu = s * (1.f / D);
  float q = 0.f;
  #pragma unroll
  for (int i=0;i<VPT;++i){ float d = v[i] - mu; q += d * d; }
  #pragma unroll
  for (int off=1; off<64; off<<=1) q += __shfl_xor(q, off);
  float rs = rsqrtf(q * (1.f / D) + 1e-5f);
  float msk = (st[token] == eid) ? 1.f : 0.f;
  #pragma unroll
  for (int i=0;i<VPT;++i){
    float gg = g[lane*VPT + i];
    float bb = beta[lane*VPT + i];
    float val = (gg * (v[i] - mu) * rs + bb) * msk;
    outp[(size_t)token * D + lane * VPT + i] = val;
    row[i] = f2bf(val);
  }
}

__global__ __launch_bounds__(256, 4)
void ln_expert(u16* __restrict__ S2,
               const float* __restrict__ g0, const float* __restrict__ be0,
               const float* __restrict__ g1, const float* __restrict__ be1,
               const float* __restrict__ g2, const float* __restrict__ be2,
               const int* __restrict__ st,
               float* __restrict__ o0, float* __restrict__ o1,
               float* __restrict__ o2)
{
  if (blockIdx.y == 0)      ln_body_masked<128>(S2,     896, g0, be0, st, 0, o0);
  else if (blockIdx.y == 1) ln_body_masked<256>(S2+128, 896, g1, be1, st, 1, o1);
  else                      ln_body_masked<512>(S2+384, 896, g2, be2, st, 2, o2);
}

__global__ __launch_bounds__(256, 4)
void ln_int(const u16* __restrict__ H, const float* __restrict__ g,
            const float* __restrict__ beta, u16* __restrict__ outp)
{
  const int tid = threadIdx.x, lane = tid & 63, wave = tid >> 6;
  const int token = blockIdx.x * 4 + wave;
  constexpr int D = 1024, VPT = 16;
  float v[VPT];
  const u16* row = H + (size_t)token * D + lane * VPT;
  #pragma unroll
  for (int i=0;i<VPT/2;++i){
    u32 u = ((const u32*)row)[i];
    v[2*i]   = bf2f((u16)(u & 0xFFFFu));
    v[2*i+1] = bf2f((u16)(u >> 16));
  }
  float s = 0.f;
  #pragma unroll
  for (int i=0;i<VPT;++i) s += v[i];
  #pragma unroll
  for (int off=1; off<64; off<<=1) s += __shfl_xor(s, off);
  float mu = s * (1.f / D);
  float q = 0.f;
  #pragma unroll
  for (int i=0;i<VPT;++i){ float d = v[i] - mu; q += d * d; }
  #pragma unroll
  for (int off=1; off<64; off<<=1) q += __shfl_xor(q, off);
  float rs = rsqrtf(q * (1.f / D) + 1e-5f);
  #pragma unroll
  for (int i=0;i<VPT;++i){
    float val = g[lane*VPT + i] * (v[i] - mu) * rs + beta[lane*VPT + i];
    outp[(size_t)token * D + lane * VPT + i] = f2bf(val);
  }
}

// ---------------- flash attention v12 (v10 + XCD-grouped block remap) ------
// 1D grid of 1024 blocks; wgid = (bh>>3)*256 + qt*8 + (bh&7) so the 32
// q-tiles of each (b,h) share one XCD's L2 (K/V fetched once per XCD, not 8x).
__global__ __launch_bounds__(256, 4)
void flash_attn(const u16* __restrict__ qkv, const u16* __restrict__ vt,
                u16* __restrict__ o)
{
  __shared__ __align__(16) u16 Ks[8192];
  __shared__ __align__(16) u16 Vs[8192];
  __shared__ __align__(16) u16 Ps[4*1024];
  const int tid = threadIdx.x, lane = tid & 63, wave = tid >> 6;
  // decode XCD-grouped wgid
  const int wgid = blockIdx.x;
  const int bh = (wgid >> 8) * 8 + (wgid & 7);
  const int b = bh >> 3, h = bh & 7, q0 = ((wgid >> 3) & 31) * 64;
  const float cl2   = 0.12751791892f;
  const float DEFER = 90.50966799187809f;

  bf16x8 qreg[4];
  {
    const u16* qrow = qkv + (size_t)(b*2048 + q0 + wave*16 + (lane&15))*3072
                      + h*128 + (lane>>4)*8;
    #pragma unroll
    for (int kk=0;kk<4;++kk) qreg[kk] = *(const bf16x8*)(qrow + kk*32);
  }
  asm volatile("s_waitcnt vmcnt(0)" ::: "memory");

  const u16* ksrc[4]; const u16* vsrc[4]; int cdst[4];
  #pragma unroll
  for (int i=0;i<4;++i){
    int cidx = (wave*4 + i)*64 + lane;
    int krow = cidx >> 4, kcs = cidx & 15;
    int kcsrc = (kcs & 8) | ((kcs & 7) ^ (krow & 7));
    ksrc[i] = qkv + (size_t)(b*2048 + krow)*3072 + h*128 + 1024 + kcsrc*8;
    int vd = cidx >> 3, vcs = cidx & 7;
    vsrc[i] = vt + ((size_t)(b*8 + h)*128 + vd)*2048 + (vcs ^ (vd & 7))*8;
    cdst[i] = cidx * 8;
  }

  int koff[16];
  #pragma unroll
  for (int kk=0;kk<4;++kk)
    #pragma unroll
    for (int cb=0;cb<4;++cb){
      int row  = (lane&15) + 16*cb;
      int c    = kk*4 + (lane>>4);
      int slot = (c & 8) | ((c & 7) ^ (row & 7));
      koff[kk*4+cb] = (row*128 + slot*8) * 2;
    }
  int voff[16];
  #pragma unroll
  for (int kk=0;kk<2;++kk)
    #pragma unroll
    for (int f=0;f<8;++f){
      int d = f*16 + (lane&15);
      int c = kk*4 + (lane>>4);
      voff[kk*8+f] = (d*64 + (c ^ (d & 7))*8) * 2;
    }
  int pwoff[8];
  #pragma unroll
  for (int e=0;e<4;++e){
    int prow = (lane>>4)*4 + e;
    int j01 = lane & 15;
    int j23 = 16 + (lane & 15);
    pwoff[e*2]   = (prow*32 + (((((j01>>2) ^ (prow&7)) & 7)<<2) | (j01&3))) * 4;
    pwoff[e*2+1] = (prow*32 + (((((j23>>2) ^ (prow&7)) & 7)<<2) | (j23&3))) * 4;
  }
  int proff[2];
  #pragma unroll
  for (int kk=0;kk<2;++kk){
    int prow = lane & 15;
    int pc   = kk*4 + (lane>>4);
    proff[kk] = (prow*64 + ((pc ^ (prow & 7)) & 7)*8) * 2;
  }

  auto stageK = [&](){
    #pragma unroll
    for (int i=0;i<4;++i){ gload_lds16(ksrc[i], Ks + cdst[i]); ksrc[i] += 196608; }
  };
  auto stageV = [&](){
    #pragma unroll
    for (int i=0;i<4;++i){ gload_lds16(vsrc[i], Vs + cdst[i]); vsrc[i] += 64; }
  };

  f32x4 oacc[8];
  #pragma unroll
  for (int f=0;f<8;++f)
    #pragma unroll
    for (int e=0;e<4;++e) oacc[f][e] = 0.f;
  float m_run[4] = {-3e38f,-3e38f,-3e38f,-3e38f};
  float l_run[4] = {0.f,0.f,0.f,0.f};
  const char* KsB = (const char*)Ks;
  const char* VsB = (const char*)Vs;
  char* PsWB = (char*)(Ps + wave*1024);

  stageK();
  stageV();
  asm volatile("s_waitcnt vmcnt(4)" ::: "memory");
  __builtin_amdgcn_s_barrier();
  __builtin_amdgcn_sched_barrier(0);

  for (int kt=0; kt<32; ++kt){
    f32x4 s[4];
    #pragma unroll
    for (int cb=0;cb<4;++cb)
      #pragma unroll
      for (int e=0;e<4;++e) s[cb][e] = 0.f;
    __builtin_amdgcn_s_setprio(1);
    #pragma unroll
    for (int kk=0;kk<4;++kk){
      #pragma unroll
      for (int cb=0;cb<4;++cb){
        bf16x8 bk = *(const bf16x8*)(KsB + koff[kk*4+cb]);
        s[cb] = __builtin_amdgcn_mfma_f32_16x16x32_bf16(qreg[kk], bk, s[cb], 0,0,0);
      }
    }
    __builtin_amdgcn_s_setprio(0);
    asm volatile("s_waitcnt lgkmcnt(0)" ::: "memory");
    __builtin_amdgcn_sched_barrier(0);
    __builtin_amdgcn_s_barrier();
    __builtin_amdgcn_sched_barrier(0);
    stageK();

    #pragma unroll
    for (int e=0;e<4;++e){
      float t0 = s[0][e], t1 = s[1][e], t2 = s[2][e], t3 = s[3][e];
      float lmx = fmaxf(fmaxf(t0,t1), fmaxf(t2,t3));
      if (__any(lmx > m_run[e] + DEFER)){
        float mx = lmx;
        #pragma unroll
        for (int off=1; off<16; off<<=1) mx = fmaxf(mx, __shfl_xor(mx, off));
        float mnew = fmaxf(m_run[e], mx);
        float a = exp2f((m_run[e] - mnew) * cl2);
        m_run[e] = mnew;
        l_run[e] *= a;
        #pragma unroll
        for (int f=0;f<8;++f) oacc[f][e] *= a;
      }
      float ms = m_run[e];
      float p0 = exp2f((t0 - ms)*cl2), p1 = exp2f((t1 - ms)*cl2);
      float p2 = exp2f((t2 - ms)*cl2), p3 = exp2f((t3 - ms)*cl2);
      l_run[e] += (p0 + p1) + (p2 + p3);
      u32 c01, c23;
      asm("v_cvt_pk_bf16_f32 %0, %1, %2" : "=v"(c01) : "v"(p0), "v"(p1));
      asm("v_cvt_pk_bf16_f32 %0, %1, %2" : "=v"(c23) : "v"(p2), "v"(p3));
      *(u32*)(PsWB + pwoff[e*2])   = c01;
      *(u32*)(PsWB + pwoff[e*2+1]) = c23;
    }

    asm volatile("s_waitcnt vmcnt(4)" ::: "memory");
    __builtin_amdgcn_sched_barrier(0);
    __builtin_amdgcn_s_barrier();
    __builtin_amdgcn_sched_barrier(0);

    __builtin_amdgcn_s_setprio(1);
    #pragma unroll
    for (int kk=0;kk<2;++kk){
      bf16x8 pa = *(const bf16x8*)(PsWB + proff[kk]);
      #pragma unroll
      for (int f=0;f<8;++f){
        bf16x8 vb = *(const bf16x8*)(VsB + voff[kk*8+f]);
        oacc[f] = __builtin_amdgcn_mfma_f32_16x16x32_bf16(pa, vb, oacc[f], 0,0,0);
      }
    }
    __builtin_amdgcn_s_setprio(0);
    asm volatile("s_waitcnt lgkmcnt(0) vmcnt(0)" ::: "memory");
    __builtin_amdgcn_sched_barrier(0);
    __builtin_amdgcn_s_barrier();
    __builtin_amdgcn_sched_barrier(0);
    if (kt + 1 < 32) stageV();
  }

  #pragma unroll
  for (int e=0;e<4;++e){
    float l = l_run[e];
    #pragma unroll
    for (int off=1; off<16; off<<=1) l += __shfl_xor(l, off);
    l_run[e] = 1.f / l;
  }
  #pragma unroll
  for (int f=0;f<8;++f)
    #pragma unroll
    for (int e=0;e<4;++e){
      int row = q0 + wave*16 + (lane>>4)*4 + e;
      int col = h*128 + f*16 + (lane&15);
      o[(size_t)(b*2048 + row)*1024 + col] = f2bf(oacc[f][e] * l_run[e]);
    }
}

// ---------------- launch ----------------
extern "C" void kernel_launch(void* const* d_in, const int* in_sizes, int n_in,
                              void* d_out, int out_size, void* d_ws, size_t ws_size,
                              hipStream_t stream)
{
  const float* x         = (const float*)d_in[0];
  const int*   stypes    = (const int*)d_in[1];
  const float* mol_W1    = (const float*)d_in[2];
  const float* mol_b1    = (const float*)d_in[3];
  const float* mol_W2    = (const float*)d_in[4];
  const float* mol_b2    = (const float*)d_in[5];
  const float* mol_g     = (const float*)d_in[6];
  const float* mol_beta  = (const float*)d_in[7];
  const float* path_W1   = (const float*)d_in[8];
  const float* path_b1   = (const float*)d_in[9];
  const float* path_W2   = (const float*)d_in[10];
  const float* path_b2   = (const float*)d_in[11];
  const float* path_g    = (const float*)d_in[12];
  const float* path_beta = (const float*)d_in[13];
  const float* cell_W1   = (const float*)d_in[14];
  const float* cell_b1   = (const float*)d_in[15];
  const float* cell_W2   = (const float*)d_in[16];
  const float* cell_b2   = (const float*)d_in[17];
  const float* cell_g    = (const float*)d_in[18];
  const float* cell_beta = (const float*)d_in[19];
  const float* int_W1    = (const float*)d_in[20];
  const float* int_b1    = (const float*)d_in[21];
  const float* int_W2    = (const float*)d_in[22];
  const float* int_b2    = (const float*)d_in[23];
  const float* int_g     = (const float*)d_in[24];
  const float* int_beta  = (const float*)d_in[25];
  const float* attn_Wqkv = (const float*)d_in[26];
  const float* attn_bqkv = (const float*)d_in[27];
  const float* attn_Wo   = (const float*)d_in[28];
  const float* attn_bo   = (const float*)d_in[29];
  const float* scale_w   = (const float*)d_in[30];

  float* out_final = (float*)d_out;           // [8192,1024] f32
  float* out_mol   = out_final + 8388608;     // [8192,128]  f32
  float* out_path  = out_mol   + 1048576;     // [8192,256]  f32
  float* out_cell  = out_path  + 2097152;     // [8192,512]  f32

  u16* ws    = (u16*)d_ws;
  u16* qkv   = ws;                  // 8192*3072 (early: xb; V third unused)
  u16* integ = qkv   + 25165824;    // 8192*1024
  u16* S1    = integ + 8388608;     // 8192*1024 scratch
  u16* S2    = S1    + 8388608;     // 8192*1024 scratch (cat / later vt)
  u16* wb    = S2    + 8388608;     // bf16 weights
  u16* xb    = qkv;                 // [8192,1024] bf16 (dead before qkv GEMM)

  u16* w1f    = wb;                  // fused expert W1 [896][1024]
  u16* molW2b = w1f    + 917504;
  u16* pathW2b= molW2b + 16384;
  u16* cellW2b= pathW2b+ 65536;
  u16* intW1b = cellW2b+ 262144;
  u16* intW2b = intW1b + 917504;
  u16* qkvWb  = intW2b + 1048576;
  u16* woWb   = qkvWb  + 3145728;
  float* fbias= (float*)(woWb + 1048576);  // 896 f32

  dim3 blk(256);
  dim3 blk2(512);

  ConvArgs ca;
  const float* srcs[11] = {x, mol_W1, path_W1, cell_W1, mol_W2, path_W2,
                           cell_W2, int_W1, int_W2, attn_Wqkv, attn_Wo};
  u16* dsts[11] = {xb, w1f, w1f + 131072, w1f + 393216, molW2b, pathW2b,
                   cellW2b, intW1b, intW2b, qkvWb, woWb};
  u32 n8s[11] = {1048576, 16384, 32768, 65536, 2048, 8192,
                 32768, 114688, 131072, 393216, 131072};
  u32 acc8 = 0;
  for (int i=0;i<11;++i){ ca.src[i]=srcs[i]; ca.dst[i]=dsts[i]; ca.base[i]=acc8; acc8+=n8s[i]; }
  ca.base[11] = acc8;
  ca.b0 = mol_b1; ca.b1 = path_b1; ca.b2 = cell_b1; ca.fbias = fbias;
  f32_to_bf16_multi<<<(acc8 + 255)/256 + 1, blk, 0, stream>>>(ca);

  // fused expert W1: silu(x @ W1f^T + b1f) -> S1 [8192,896]   (256x128 tiles)
  gemm_bt2<1><<<dim3(7,32), blk2, 0, stream>>>(xb, w1f, fbias, S1, 896, 1024, 1024, 896, nullptr, nullptr);
  // grouped expert W2 -> S2 [8192,896]  (legacy 128x128)
  gemm_w2group<<<448, blk, 0, stream>>>(S1, S2, molW2b, pathW2b, cellW2b,
                                        mol_b2, path_b2, cell_b2);
  // grouped expert LNs
  ln_expert<<<dim3(2048,3), blk, 0, stream>>>(S2, mol_g, mol_beta, path_g,
                                              path_beta, cell_g, cell_beta,
                                              stypes, out_mol, out_path, out_cell);

  // integration (256x128 tiles)
  gemm_bt2<1><<<dim3(8,32), blk2, 0, stream>>>(S2, intW1b, int_b1, S1, 1024, 896,  896,  1024, nullptr, nullptr);
  gemm_bt2<0><<<dim3(8,32), blk2, 0, stream>>>(S1, intW2b, int_b2, S2, 1024, 1024, 1024, 1024, nullptr, nullptr);
  ln_int<<<2048, blk, 0, stream>>>(S2, int_g, int_beta, integ);

  // attention: grouped Q|K (512 blk) + V^T (256 blk, coalesced epilogue)
  gemm_qkv_vt2<<<768, blk2, 0, stream>>>(integ, qkvWb, attn_bqkv, qkv, S2);
  flash_attn<<<1024, blk, 0, stream>>>(qkv, S2, S1);

  // final = integ + w0*(o @ Wo^T + bo), f32 out (256x128 tiles)
  gemm_bt2<2><<<dim3(8,32), blk2, 0, stream>>>(S1, woWb, attn_bo, out_final, 1024, 1024, 1024, 1024, integ, scale_w);
}